// Round 8
// baseline (39.125 us; speedup 1.0000x reference)
//
#include <hip/hip_runtime.h>

#define WINDOW 11
#define H 512
#define W 512
#define OH 502            // H - WINDOW + 1
#define OW 502
#define NCH 3
#define BATCH 8
#define RSTRIPE 8
#define NSTRIPES 63       // 62 x 8 rows + 1 x 6 rows (both even trip counts)
#define NGRP 5            // col groups: 4 x 118 outputs + 1 x 30
#define GRPW 118          // output cols per full group (64 lanes * 2 - 10 halo)
#define WAVES_PER_IMG (NSTRIPES * NGRP)                 // 315
#define NWAVES (BATCH * NCH * WAVES_PER_IMG)            // 7560
#define NBLOCKS (NWAVES / 4)                            // 1890
#define WAVES_PER_BATCH (NCH * WAVES_PER_IMG)           // 945

#define NPIX_PER_BATCH (3.0f * 502.0f * 502.0f)   // 756012

// ---- gfx9 DPP inclusive wave scan (64 lanes), VALU-pipe only ----
template <int CTRL, int RM>
__device__ __forceinline__ float scan_step(float x) {
    int s = __builtin_amdgcn_update_dpp(0, __builtin_bit_cast(int, x),
                                        CTRL, RM, 0xf, false);
    return x + __builtin_bit_cast(float, s);
}
__device__ __forceinline__ float wave_iscan(float x) {
    x = scan_step<0x111, 0xf>(x);   // row_shr:1
    x = scan_step<0x112, 0xf>(x);   // row_shr:2
    x = scan_step<0x114, 0xf>(x);   // row_shr:4
    x = scan_step<0x118, 0xf>(x);   // row_shr:8
    x = scan_step<0x142, 0xa>(x);   // row_bcast:15 -> rows 1,3
    x = scan_step<0x143, 0xc>(x);   // row_bcast:31 -> rows 2,3
    return x;
}

__device__ __forceinline__ float ssim_from(float sx, float sy, float s2, float sxy) {
    const float n = 121.0f;
    const float inv_n = 1.0f / 121.0f;
    const float inv_nm1 = 1.0f / 120.0f;
    const float c1 = 1e-4f;   // (0.01)^2
    const float c2 = 9e-4f;   // (0.03)^2
    float mx  = sx * inv_n;
    float my  = sy * inv_n;
    float mxy = mx * my;
    float m2  = mx * mx + my * my;
    float cov = (sxy - n * mxy) * inv_nm1;   // covariance
    float v2  = (s2  - n * m2)  * inv_nm1;   // vx + vy
    float num = (2.f * mxy + c1) * (2.f * cov + c2);
    float den = (m2 + c1) * (v2 + c2);
    return num * __builtin_amdgcn_rcpf(den);  // den >= 9e-8, rel err ~1e-7
}

__global__ __launch_bounds__(256, 6) void ssim_main(const float* __restrict__ x,
                                                    const float* __restrict__ y,
                                                    float* __restrict__ partials) {
    const int t    = threadIdx.x;
    const int widx = t >> 6;
    const int lane = t & 63;
    const int w    = blockIdx.x * 4 + widx;    // global wave id

    const int grp = w % NGRP;
    const int rs  = (w / NGRP) % NSTRIPES;
    const int img = w / WAVES_PER_IMG;         // b*NCH + c

    const int i0 = rs * RSTRIPE;
    const int i1 = min(i0 + RSTRIPE, OH);      // 8 rows; stripe 62: 6 rows (even)
    const int cstart = grp * GRPW;             // first staged/output col
    const int outw   = min(GRPW, OW - cstart); // 118 or 30
    // clamped column pair: out-of-range lanes read real (unused) data
    const int c0 = min(cstart + 2 * lane, W - 2);
    const bool tapActive = (2 * lane < outw);

    const float* __restrict__ xi = x + (size_t)img * H * W;
    const float* __restrict__ yi = y + (size_t)img * H * W;
    const float* xc = xi + c0;                 // this lane's column base
    const float* yc = yi + c0;

    // --- init: vertical column sums for rows i0..i0+10, in registers ---
    float4 v0 = make_float4(0.f, 0.f, 0.f, 0.f);
    float4 v1 = make_float4(0.f, 0.f, 0.f, 0.f);
#pragma unroll
    for (int r = 0; r < WINDOW; ++r) {
        float2 a = *(const float2*)(xc + (size_t)(i0 + r) * W);
        float2 b = *(const float2*)(yc + (size_t)(i0 + r) * W);
        v0.x += a.x; v0.y += b.x; v0.z += a.x * a.x + b.x * b.x; v0.w += a.x * b.x;
        v1.x += a.y; v1.y += b.y; v1.z += a.y * a.y + b.y * b.y; v1.w += a.y * b.y;
    }

    // slide loads for iteration j: old row j, new row j+11 (rows clamped; any
    // clamped load feeds only windows whose results are never accumulated)
#define LD(j, xo, yo, xn, yn) do {                                  \
        int jc_ = min((j), H - 1);                                   \
        int rn_ = min((j) + WINDOW, H - 1);                          \
        xo = *(const float2*)(xc + (size_t)jc_ * W);                 \
        yo = *(const float2*)(yc + (size_t)jc_ * W);                 \
        xn = *(const float2*)(xc + (size_t)rn_ * W);                 \
        yn = *(const float2*)(yc + (size_t)rn_ * W);                 \
    } while (0)

#define SLIDE(xo, yo, xn, yn) do {                                   \
        v0.x += xn.x - xo.x;                                          \
        v0.y += yn.x - yo.x;                                          \
        v0.z += xn.x * xn.x + yn.x * yn.x - xo.x * xo.x - yo.x * yo.x;\
        v0.w += xn.x * yn.x - xo.x * yo.x;                            \
        v1.x += xn.y - xo.y;                                          \
        v1.y += yn.y - yo.y;                                          \
        v1.z += xn.y * xn.y + yn.y * yn.y - xo.y * xo.y - yo.y * yo.y;\
        v1.w += xn.y * yn.y - xo.y * yo.y;                            \
    } while (0)

    float acc = 0.f;

#define COMPUTE() do {                                                        \
        float Tx = v0.x + v1.x, Ty = v0.y + v1.y;                             \
        float Tz = v0.z + v1.z, Tw = v0.w + v1.w;                             \
        float Sx = wave_iscan(Tx), Sy = wave_iscan(Ty);                       \
        float Sz = wave_iscan(Tz), Sw = wave_iscan(Tw);                       \
        int src = lane + 5;                                                   \
        float Ax = __shfl(Sx, src, 64), Ay = __shfl(Sy, src, 64);             \
        float Az = __shfl(Sz, src, 64), Aw = __shfl(Sw, src, 64);             \
        float Bx = __shfl(v1.x, src, 64), By = __shfl(v1.y, src, 64);         \
        float Bz = __shfl(v1.z, src, 64), Bw = __shfl(v1.w, src, 64);         \
        if (tapActive) {                                                      \
            acc += ssim_from(Ax - Bx - Sx + Tx, Ay - By - Sy + Ty,            \
                             Az - Bz - Sz + Tz, Aw - Bw - Sw + Tw);           \
            acc += ssim_from(Ax - Sx + v1.x, Ay - Sy + v1.y,                  \
                             Az - Sz + v1.z, Aw - Sw + v1.w);                 \
        }                                                                     \
    } while (0)

    // --- depth-2 software-pipelined main loop (best known structure, R6) ---
    float2 xoA, yoA, xnA, ynA, xoB, yoB, xnB, ynB;
    LD(i0,     xoA, yoA, xnA, ynA);
    LD(i0 + 1, xoB, yoB, xnB, ynB);
    for (int i = i0; i < i1; i += 2) {
        COMPUTE();                       // row i
        SLIDE(xoA, yoA, xnA, ynA);       // -> window for row i+1
        LD(i + 2, xoA, yoA, xnA, ynA);   // prefetch iter i+2 (clamped)
        COMPUTE();                       // row i+1
        SLIDE(xoB, yoB, xnB, ynB);       // -> window for row i+2
        LD(i + 3, xoB, yoB, xnB, ynB);   // prefetch iter i+3 (clamped)
    }

    // --- per-wave reduction only (no cross-wave coupling, no barriers) ---
    for (int off = 32; off > 0; off >>= 1)
        acc += __shfl_down(acc, off, 64);
    if (lane == 0) partials[w] = acc;
}

__global__ __launch_bounds__(256) void ssim_reduce(const float* __restrict__ partials,
                                                   float* __restrict__ out) {
    const int b = blockIdx.x;              // one block per batch element
    const int t = threadIdx.x;
    float s = 0.f;
    for (int k = t; k < WAVES_PER_BATCH; k += 256)   // 945 per batch
        s += partials[b * WAVES_PER_BATCH + k];
    for (int off = 32; off > 0; off >>= 1)
        s += __shfl_down(s, off, 64);
    __shared__ float red[4];
    int wid = t >> 6, lane = t & 63;
    if (lane == 0) red[wid] = s;
    __syncthreads();
    if (t == 0) {
        float tot = (red[0] + red[1]) + (red[2] + red[3]);
        out[b] = (1.0f - tot / NPIX_PER_BATCH) * 0.5f;
    }
}

extern "C" void kernel_launch(void* const* d_in, const int* in_sizes, int n_in,
                              void* d_out, int out_size, void* d_ws, size_t ws_size,
                              hipStream_t stream) {
    const float* x = (const float*)d_in[0];
    const float* y = (const float*)d_in[1];
    float* out      = (float*)d_out;
    float* partials = (float*)d_ws;   // 7560 floats, fully overwritten each call

    ssim_main<<<NBLOCKS, 256, 0, stream>>>(x, y, partials);
    ssim_reduce<<<BATCH, 256, 0, stream>>>(partials, out);
}

// Round 9
// 27.450 us; speedup vs baseline: 1.4253x; 1.4253x over previous
//
#include <hip/hip_runtime.h>

#define WINDOW 11
#define H 512
#define W 512
#define OH 502            // H - WINDOW + 1
#define OW 502
#define NCH 3
#define BATCH 8
#define RSTRIPE 32
#define NSTRIPES 16       // 15 x 32 rows + 1 x 22 rows (both even trip counts)
#define NGRP 5            // col groups: 4 x 118 outputs + 1 x 30
#define GRPW 118          // output cols per full group (64 lanes * 2 - 10 halo)
#define WAVES_PER_IMG (NSTRIPES * NGRP)                 // 80
#define NWAVES (BATCH * NCH * WAVES_PER_IMG)            // 1920
#define WAVES_PER_BATCH (NCH * WAVES_PER_IMG)           // 240
#define NXCD 8
#define CHUNK (NWAVES / NXCD)                           // 240

#define NPIX_PER_BATCH (3.0f * 502.0f * 502.0f)   // 756012

// ---- gfx9 DPP inclusive wave scan (64 lanes), VALU-pipe only ----
template <int CTRL, int RM>
__device__ __forceinline__ float scan_step(float x) {
    int s = __builtin_amdgcn_update_dpp(0, __builtin_bit_cast(int, x),
                                        CTRL, RM, 0xf, false);
    return x + __builtin_bit_cast(float, s);
}
__device__ __forceinline__ float wave_iscan(float x) {
    x = scan_step<0x111, 0xf>(x);   // row_shr:1
    x = scan_step<0x112, 0xf>(x);   // row_shr:2
    x = scan_step<0x114, 0xf>(x);   // row_shr:4
    x = scan_step<0x118, 0xf>(x);   // row_shr:8
    x = scan_step<0x142, 0xa>(x);   // row_bcast:15 -> rows 1,3
    x = scan_step<0x143, 0xc>(x);   // row_bcast:31 -> rows 2,3
    return x;
}

__device__ __forceinline__ float ssim_from(float sx, float sy, float s2, float sxy) {
    const float n = 121.0f;
    const float inv_n = 1.0f / 121.0f;
    const float inv_nm1 = 1.0f / 120.0f;
    const float c1 = 1e-4f;   // (0.01)^2
    const float c2 = 9e-4f;   // (0.03)^2
    float mx  = sx * inv_n;
    float my  = sy * inv_n;
    float mxy = mx * my;
    float m2  = mx * mx + my * my;
    float cov = (sxy - n * mxy) * inv_nm1;   // covariance
    float v2  = (s2  - n * m2)  * inv_nm1;   // vx + vy
    float num = (2.f * mxy + c1) * (2.f * cov + c2);
    float den = (m2 + c1) * (v2 + c2);
    return num * __builtin_amdgcn_rcpf(den);  // den >= 9e-8, rel err ~1e-7
}

__global__ __launch_bounds__(64) void ssim_main(const float* __restrict__ x,
                                                const float* __restrict__ y,
                                                float* __restrict__ partials) {
    const int lane = threadIdx.x & 63;

    // XCD-chunked bijective swizzle: consecutive stripes of one (img,grp)
    // band land on the same XCD -> halo rows and old-row re-reads L2-hit.
    const int wg    = blockIdx.x;               // 0..1919, round-robins XCDs
    const int w_lin = (wg % NXCD) * CHUNK + wg / NXCD;

    const int img = w_lin / WAVES_PER_IMG;      // b*NCH + c
    const int rem = w_lin % WAVES_PER_IMG;
    const int grp = rem / NSTRIPES;
    const int rs  = rem % NSTRIPES;             // stripe minor -> XCD-contiguous

    const int i0 = rs * RSTRIPE;
    const int i1 = min(i0 + RSTRIPE, OH);       // 32 rows; stripe 15: 22 (even)
    const int cstart = grp * GRPW;              // first staged/output col
    const int outw   = min(GRPW, OW - cstart);  // 118 or 30
    // clamped column pair: out-of-range lanes read real (unused) data
    const int c0 = min(cstart + 2 * lane, W - 2);
    const bool tapActive = (2 * lane < outw);

    const float* __restrict__ xi = x + (size_t)img * H * W;
    const float* __restrict__ yi = y + (size_t)img * H * W;
    const float* xc = xi + c0;                  // this lane's column base
    const float* yc = yi + c0;

    // --- init: vertical column sums for rows i0..i0+10, in registers ---
    float4 v0 = make_float4(0.f, 0.f, 0.f, 0.f);
    float4 v1 = make_float4(0.f, 0.f, 0.f, 0.f);
#pragma unroll
    for (int r = 0; r < WINDOW; ++r) {
        float2 a = *(const float2*)(xc + (size_t)(i0 + r) * W);
        float2 b = *(const float2*)(yc + (size_t)(i0 + r) * W);
        v0.x += a.x; v0.y += b.x; v0.z += a.x * a.x + b.x * b.x; v0.w += a.x * b.x;
        v1.x += a.y; v1.y += b.y; v1.z += a.y * a.y + b.y * b.y; v1.w += a.y * b.y;
    }

    // slide loads for iteration j: old row j, new row j+11 (rows clamped; any
    // clamped load feeds only windows whose results are never accumulated)
#define LD(j, xo, yo, xn, yn) do {                                  \
        int jc_ = min((j), H - 1);                                   \
        int rn_ = min((j) + WINDOW, H - 1);                          \
        xo = *(const float2*)(xc + (size_t)jc_ * W);                 \
        yo = *(const float2*)(yc + (size_t)jc_ * W);                 \
        xn = *(const float2*)(xc + (size_t)rn_ * W);                 \
        yn = *(const float2*)(yc + (size_t)rn_ * W);                 \
    } while (0)

#define SLIDE(xo, yo, xn, yn) do {                                   \
        v0.x += xn.x - xo.x;                                          \
        v0.y += yn.x - yo.x;                                          \
        v0.z += xn.x * xn.x + yn.x * yn.x - xo.x * xo.x - yo.x * yo.x;\
        v0.w += xn.x * yn.x - xo.x * yo.x;                            \
        v1.x += xn.y - xo.y;                                          \
        v1.y += yn.y - yo.y;                                          \
        v1.z += xn.y * xn.y + yn.y * yn.y - xo.y * xo.y - yo.y * yo.y;\
        v1.w += xn.y * yn.y - xo.y * yo.y;                            \
    } while (0)

    float acc = 0.f;

#define COMPUTE() do {                                                        \
        float Tx = v0.x + v1.x, Ty = v0.y + v1.y;                             \
        float Tz = v0.z + v1.z, Tw = v0.w + v1.w;                             \
        float Sx = wave_iscan(Tx), Sy = wave_iscan(Ty);                       \
        float Sz = wave_iscan(Tz), Sw = wave_iscan(Tw);                       \
        int src = lane + 5;                                                   \
        float Ax = __shfl(Sx, src, 64), Ay = __shfl(Sy, src, 64);             \
        float Az = __shfl(Sz, src, 64), Aw = __shfl(Sw, src, 64);             \
        float Bx = __shfl(v1.x, src, 64), By = __shfl(v1.y, src, 64);         \
        float Bz = __shfl(v1.z, src, 64), Bw = __shfl(v1.w, src, 64);         \
        if (tapActive) {                                                      \
            acc += ssim_from(Ax - Bx - Sx + Tx, Ay - By - Sy + Ty,            \
                             Az - Bz - Sz + Tz, Aw - Bw - Sw + Tw);           \
            acc += ssim_from(Ax - Sx + v1.x, Ay - Sy + v1.y,                  \
                             Az - Sz + v1.z, Aw - Sw + v1.w);                 \
        }                                                                     \
    } while (0)

    // --- depth-2 software-pipelined main loop (best known structure, R6) ---
    float2 xoA, yoA, xnA, ynA, xoB, yoB, xnB, ynB;
    LD(i0,     xoA, yoA, xnA, ynA);
    LD(i0 + 1, xoB, yoB, xnB, ynB);
    for (int i = i0; i < i1; i += 2) {
        COMPUTE();                       // row i
        SLIDE(xoA, yoA, xnA, ynA);       // -> window for row i+1
        LD(i + 2, xoA, yoA, xnA, ynA);   // prefetch iter i+2 (clamped)
        COMPUTE();                       // row i+1
        SLIDE(xoB, yoB, xnB, ynB);       // -> window for row i+2
        LD(i + 3, xoB, yoB, xnB, ynB);   // prefetch iter i+3 (clamped)
    }

    // --- per-wave reduction (fixed order, deterministic), no LDS/barriers ---
    for (int off = 32; off > 0; off >>= 1)
        acc += __shfl_down(acc, off, 64);
    if (lane == 0) partials[w_lin] = acc;   // batch-contiguous layout
}

__global__ __launch_bounds__(256) void ssim_reduce(const float* __restrict__ partials,
                                                   float* __restrict__ out) {
    const int b = blockIdx.x;              // one block per batch element
    const int t = threadIdx.x;
    float s = 0.f;
    for (int k = t; k < WAVES_PER_BATCH; k += 256)   // 240 per batch
        s += partials[b * WAVES_PER_BATCH + k];
    for (int off = 32; off > 0; off >>= 1)
        s += __shfl_down(s, off, 64);
    __shared__ float red[4];
    int wid = t >> 6, lane = t & 63;
    if (lane == 0) red[wid] = s;
    __syncthreads();
    if (t == 0) {
        float tot = (red[0] + red[1]) + (red[2] + red[3]);
        out[b] = (1.0f - tot / NPIX_PER_BATCH) * 0.5f;
    }
}

extern "C" void kernel_launch(void* const* d_in, const int* in_sizes, int n_in,
                              void* d_out, int out_size, void* d_ws, size_t ws_size,
                              hipStream_t stream) {
    const float* x = (const float*)d_in[0];
    const float* y = (const float*)d_in[1];
    float* out      = (float*)d_out;
    float* partials = (float*)d_ws;   // 1920 floats, fully overwritten each call

    ssim_main<<<NWAVES, 64, 0, stream>>>(x, y, partials);
    ssim_reduce<<<BATCH, 256, 0, stream>>>(partials, out);
}